// Round 19
// baseline (255.123 us; speedup 1.0000x reference)
//
#include <hip/hip_runtime.h>
#include <math.h>

#define NNODE 10000
#define INCH  9998
#define NEDGE 320000
#define KSL   80           // K-slices of 128 (ks 0..79); k1 block does j,+20,+40,+60
#define WCOL  132          // padded k-stride of W slice (halves): 2-way bank alias = free
#define WSLH  10560        // halves per W slice: 80*132 (21120 B = 1320 uint4)
#define NSLAB 800000       // values per output slab (10000 x 80)
#define ZNI   20096        // ints zeroed: [deg(10048), cnt(10048)]

typedef _Float16 half8 __attribute__((ext_vector_type(8)));
typedef float    f32x4 __attribute__((ext_vector_type(4)));

__device__ __forceinline__ float lrelu(float v){ return v > 0.f ? v : 0.2f*v; }
__device__ __forceinline__ float frelu(float v){ return v > 0.f ? v : 0.f; }

#define RED1(v) { _Pragma("unroll") for (int m_ = 1; m_ < 64; m_ <<= 1) v += __shfl_xor(v, m_, 64); }

// ---------------------------------------------------------------------------
// Weight prep: Wpad[ks][col][kk] fp16, 128-K slices; zero-inits CSR counters.
__global__ void prep_wt(const float* __restrict__ Wl, const float* __restrict__ Wr,
                        const float* __restrict__ We, _Float16* __restrict__ Wpad,
                        int* __restrict__ zint){
  int idx = blockIdx.x*256 + threadIdx.x;
  if (idx < ZNI) zint[idx] = 0;
  if (idx >= KSL*WSLH) return;
  int ks  = idx / WSLH;
  int rem = idx - ks*WSLH;
  int col = rem / WCOL;
  int kk  = rem - col*WCOL;
  int k   = ks*128 + kk;
  float v = 0.f;
  if (kk < 128 && k < INCH)
    v = (col < 8) ? Wl[k*8 + col] : (col < 16 ? Wr[k*8 + (col-8)] : We[k*64 + (col-16)]);
  Wpad[idx] = (_Float16)v;
}

// ---------------------------------------------------------------------------
// k1 (r15 structure; r18 TLP: 128-K slices -> 21.1KB LDS -> 5 blocks/CU =
// 20 waves/CU). r19 fix: W-slice copy count 660 -> 1320 uint4s (r18 loaded
// only HALF the slice — halves/16 instead of bytes/16 — cols 40..79 garbage).
#define XL(C, X0, X1, X2, X3) { \
  int kb_ = k0b + (C)*32 + 8*g; \
  X0 = *(const float2*)(x + min(xbase + kb_    , maxi)); \
  X1 = *(const float2*)(x + min(xbase + kb_ + 2, maxi)); \
  X2 = *(const float2*)(x + min(xbase + kb_ + 4, maxi)); \
  X3 = *(const float2*)(x + min(xbase + kb_ + 6, maxi)); }

#define CMP(C, X0, X1, X2, X3) { \
  half8 ah = {(_Float16)X0.x, (_Float16)X0.y, (_Float16)X1.x, (_Float16)X1.y, \
              (_Float16)X2.x, (_Float16)X2.y, (_Float16)X3.x, (_Float16)X3.y}; \
  const _Float16* wp_ = lw + (C)*32 + 8*g; \
  half8 b0 = *(const half8*)(wp_ + (c0     )*WCOL); \
  half8 b1 = *(const half8*)(wp_ + (c0 + 16)*WCOL); \
  half8 b2 = *(const half8*)(wp_ + (c0 + 32)*WCOL); \
  half8 b3 = *(const half8*)(wp_ + (c0 + 48)*WCOL); \
  half8 b4 = *(const half8*)(wp_ + (c0 + 64)*WCOL); \
  a0 = __builtin_amdgcn_mfma_f32_16x16x32_f16(ah, b0, a0, 0, 0, 0); \
  a1 = __builtin_amdgcn_mfma_f32_16x16x32_f16(ah, b1, a1, 0, 0, 0); \
  a2 = __builtin_amdgcn_mfma_f32_16x16x32_f16(ah, b2, a2, 0, 0, 0); \
  a3 = __builtin_amdgcn_mfma_f32_16x16x32_f16(ah, b3, a3, 0, 0, 0); \
  a4 = __builtin_amdgcn_mfma_f32_16x16x32_f16(ah, b4, a4, 0, 0, 0); }

__global__ __launch_bounds__(256, 5)
void k1_fused(const float* __restrict__ x, const _Float16* __restrict__ Wpad,
              _Float16* __restrict__ slabh){
  __shared__ _Float16 lw[WSLH];         // 21120 B -> 5 blocks/CU
  const int tid  = threadIdx.x;
  const int lane = tid & 63;
  const int wv   = tid >> 6;
  const int g    = lane >> 4;
  const int c0   = lane & 15;
  const int bid  = blockIdx.x;
  const int j    = bid / 157;           // output slab 0..19
  const int rb   = bid - j*157;         // row block 0..156
  const int arow = rb*64 + wv*16 + c0;
  const int xbase= (arow < NNODE ? arow : NNODE-1)*INCH;
  const int maxi = NNODE*INCH - 2;

  f32x4 a0={0,0,0,0}, a1={0,0,0,0}, a2={0,0,0,0}, a3={0,0,0,0}, a4={0,0,0,0};

  for (int h = 0; h < 4; ++h){          // 4 x 128-K phases: ks = j + 20h
    const int ks  = j + 20*h;
    const int k0b = ks << 7;
    if (h) __syncthreads();             // all waves done reading prev W slice
    {                                   // load W slice (1320 x 16B, coalesced)
      const uint4* src = (const uint4*)(Wpad + (size_t)ks*WSLH);
      uint4* dst = (uint4*)lw;
      #pragma unroll
      for (int i = 0; i < 6; ++i){
        int idx = tid + 256*i;
        if (idx < 1320) dst[idx] = src[idx];
      }
    }
    __syncthreads();                    // W visible; chunk loop barrier-free

    float2 xa0,xa1,xa2,xa3, xb0,xb1,xb2,xb3;
    XL(0, xa0,xa1,xa2,xa3)
    #pragma unroll
    for (int c = 0; c < 4; c += 2){     // 2-slot static pipeline (no reg moves)
      XL(c+1, xb0,xb1,xb2,xb3)
      CMP(c,   xa0,xa1,xa2,xa3)
      if (c + 2 < 4) XL(c+2, xa0,xa1,xa2,xa3)
      CMP(c+1, xb0,xb1,xb2,xb3)
    }
  }

  // epilogue: C/D layout col=lane&15, row=4*(lane>>4)+reg [m89-verified]
  const int nodeb = rb*64 + wv*16 + 4*g;
  #define EPI(T, A) { \
    _Pragma("unroll") \
    for (int r = 0; r < 4; ++r){ \
      int row = nodeb + r; \
      if (row < NNODE) \
        slabh[(size_t)j*NSLAB + (size_t)row*80 + 16*(T) + c0] = (_Float16)A[r]; \
    } }
  EPI(0, a0) EPI(1, a1) EPI(2, a2) EPI(3, a3) EPI(4, a4)
}

// ---------------------------------------------------------------------------
__global__ void reduce80(const _Float16* __restrict__ slabh, const float* __restrict__ bl1,
                         const float* __restrict__ br1, float* __restrict__ xl1,
                         float* __restrict__ xr1, float* __restrict__ encp){
  int f = blockIdx.x*256 + threadIdx.x;
  if (f >= NSLAB) return;
  float s = 0.f;
  #pragma unroll
  for (int k = 0; k < 20; ++k) s += (float)slabh[(size_t)k*NSLAB + f];
  int n = f / 80;
  int col = f - n*80;
  if (col < 8)       xl1[n*8 + col]        = s + bl1[col];
  else if (col < 16) xr1[n*8 + col - 8]    = s + br1[col - 8];
  else               encp[n*64 + col - 16] = s;
}

// ---------------------------------------------------------------------------
// CSR build (dst-grouped edge list incl. self-loops). deg/cnt pre-zeroed.
__global__ void csr_hist(const int* __restrict__ ei, int* __restrict__ deg){
  int e = blockIdx.x*256 + threadIdx.x;
  if (e >= NEDGE + NNODE) return;
  int d = (e < NEDGE) ? ei[NEDGE + e] : e - NEDGE;
  atomicAdd(deg + d, 1);
}

__global__ void csr_scan(const int* __restrict__ deg, int* __restrict__ offs){
  __shared__ int ssum[256];
  int t = threadIdx.x;
  int base = t*40;
  int s = 0;
  for (int i = 0; i < 40; ++i){
    int idx = base + i;
    s += (idx < NNODE) ? deg[idx] : 0;
  }
  ssum[t] = s;
  __syncthreads();
  for (int d = 1; d < 256; d <<= 1){
    int v = (t >= d) ? ssum[t - d] : 0;
    __syncthreads();
    ssum[t] += v;
    __syncthreads();
  }
  int run = (t == 0) ? 0 : ssum[t - 1];
  for (int i = 0; i < 40; ++i){
    int idx = base + i;
    if (idx < NNODE){ offs[idx] = run; run += deg[idx]; }
  }
}

__global__ void csr_scat(const int* __restrict__ ei, const int* __restrict__ offs,
                         int* __restrict__ cnt, int* __restrict__ csrc){
  int e = blockIdx.x*256 + threadIdx.x;
  if (e >= NEDGE + NNODE) return;
  int s, d;
  if (e < NEDGE){ s = ei[e]; d = ei[NEDGE + e]; } else { s = d = e - NEDGE; }
  int p = offs[d] + atomicAdd(cnt + d, 1);
  csrc[p] = s;
}

// ---------------------------------------------------------------------------
// conv1 aggregation, wave-per-dst, ONE pass, NO atomics.
__global__ __launch_bounds__(256)
void conv1_agg(const int* __restrict__ offs, const int* __restrict__ deg,
               const int* __restrict__ csrc, const float* __restrict__ xl1,
               const float* __restrict__ xr1, const float* __restrict__ att,
               const float* __restrict__ bias1, const float* __restrict__ linW,
               const float* __restrict__ linb, float* __restrict__ x1){
  int wv = threadIdx.x >> 6, lane = threadIdx.x & 63;
  int n = blockIdx.x*4 + wv;
  if (n >= NNODE) return;
  const int st = offs[n], en = st + deg[n];
  const float4 r0 = *(const float4*)(xr1 + n*8);
  const float4 r1 = *(const float4*)(xr1 + n*8 + 4);
  float at0=att[0], at1=att[1], at2=att[2], at3=att[3];
  float at4=att[4], at5=att[5], at6=att[6], at7=att[7];

  float d0=0.f, d1=0.f;
  float n0=0.f,n1=0.f,n2=0.f,n3=0.f,n4=0.f,n5=0.f,n6=0.f,n7=0.f;
  for (int i = st + lane; i < en; i += 64){
    int s = csrc[i];
    const float4 q0 = *(const float4*)(xl1 + s*8);
    const float4 q1 = *(const float4*)(xl1 + s*8 + 4);
    float l0 = at0*lrelu(q0.x+r0.x) + at1*lrelu(q0.y+r0.y)
             + at2*lrelu(q0.z+r0.z) + at3*lrelu(q0.w+r0.w);
    float l1 = at4*lrelu(q1.x+r1.x) + at5*lrelu(q1.y+r1.y)
             + at6*lrelu(q1.z+r1.z) + at7*lrelu(q1.w+r1.w);
    float e0 = expf(l0), e1 = expf(l1);
    d0 += e0; d1 += e1;
    n0 += e0*q0.x; n1 += e0*q0.y; n2 += e0*q0.z; n3 += e0*q0.w;
    n4 += e1*q1.x; n5 += e1*q1.y; n6 += e1*q1.z; n7 += e1*q1.w;
  }
  RED1(d0) RED1(d1)
  RED1(n0) RED1(n1) RED1(n2) RED1(n3)
  RED1(n4) RED1(n5) RED1(n6) RED1(n7)
  if (lane == 0){
    float acc = linb[0];
    acc = fmaf(frelu(n0/d0 + bias1[0]), linW[0], acc);
    acc = fmaf(frelu(n1/d0 + bias1[1]), linW[1], acc);
    acc = fmaf(frelu(n2/d0 + bias1[2]), linW[2], acc);
    acc = fmaf(frelu(n3/d0 + bias1[3]), linW[3], acc);
    acc = fmaf(frelu(n4/d1 + bias1[4]), linW[4], acc);
    acc = fmaf(frelu(n5/d1 + bias1[5]), linW[5], acc);
    acc = fmaf(frelu(n6/d1 + bias1[6]), linW[6], acc);
    acc = fmaf(frelu(n7/d1 + bias1[7]), linW[7], acc);
    x1[n] = acc;
  }
}

// ---------------------------------------------------------------------------
// conv2 aggregation (rank-1 from scalar x1) + x2 in-register.
__global__ __launch_bounds__(256)
void conv2_agg(const int* __restrict__ offs, const int* __restrict__ deg,
               const int* __restrict__ csrc, const float* __restrict__ x1,
               const float* __restrict__ Wl2, const float* __restrict__ bl2,
               const float* __restrict__ Wr2, const float* __restrict__ br2,
               const float* __restrict__ att, const float* __restrict__ bias2,
               const float* __restrict__ l2W, const float* __restrict__ l2b,
               float* __restrict__ x2a){
  int wv = threadIdx.x >> 6, lane = threadIdx.x & 63;
  int n = blockIdx.x*4 + wv;
  if (n >= NNODE) return;
  const int st = offs[n], en = st + deg[n];
  const float xd = x1[n];
  float wr[8], wl[8], blv[8], atv[8];
  #pragma unroll
  for (int c = 0; c < 8; ++c){
    wr[c]  = fmaf(xd, Wr2[c], br2[c]);
    wl[c]  = Wl2[c];
    blv[c] = bl2[c];
    atv[c] = att[c];
  }
  float d0=0.f, d1=0.f;
  float n0=0.f,n1=0.f,n2=0.f,n3=0.f,n4=0.f,n5=0.f,n6=0.f,n7=0.f;
  for (int i = st + lane; i < en; i += 64){
    float xs = x1[csrc[i]];
    float f0 = fmaf(xs, wl[0], blv[0]);
    float f1 = fmaf(xs, wl[1], blv[1]);
    float f2 = fmaf(xs, wl[2], blv[2]);
    float f3 = fmaf(xs, wl[3], blv[3]);
    float f4 = fmaf(xs, wl[4], blv[4]);
    float f5 = fmaf(xs, wl[5], blv[5]);
    float f6 = fmaf(xs, wl[6], blv[6]);
    float f7 = fmaf(xs, wl[7], blv[7]);
    float l0 = atv[0]*lrelu(f0+wr[0]) + atv[1]*lrelu(f1+wr[1])
             + atv[2]*lrelu(f2+wr[2]) + atv[3]*lrelu(f3+wr[3]);
    float l1 = atv[4]*lrelu(f4+wr[4]) + atv[5]*lrelu(f5+wr[5])
             + atv[6]*lrelu(f6+wr[6]) + atv[7]*lrelu(f7+wr[7]);
    float e0 = expf(l0), e1 = expf(l1);
    d0 += e0; d1 += e1;
    n0 += e0*f0; n1 += e0*f1; n2 += e0*f2; n3 += e0*f3;
    n4 += e1*f4; n5 += e1*f5; n6 += e1*f6; n7 += e1*f7;
  }
  RED1(d0) RED1(d1)
  RED1(n0) RED1(n1) RED1(n2) RED1(n3)
  RED1(n4) RED1(n5) RED1(n6) RED1(n7)
  if (lane == 0){
    float acc = l2b[0];
    acc = fmaf(frelu(n0/d0 + bias2[0]), l2W[0], acc);
    acc = fmaf(frelu(n1/d0 + bias2[1]), l2W[1], acc);
    acc = fmaf(frelu(n2/d0 + bias2[2]), l2W[2], acc);
    acc = fmaf(frelu(n3/d0 + bias2[3]), l2W[3], acc);
    acc = fmaf(frelu(n4/d1 + bias2[4]), l2W[4], acc);
    acc = fmaf(frelu(n5/d1 + bias2[5]), l2W[5], acc);
    acc = fmaf(frelu(n6/d1 + bias2[6]), l2W[6], acc);
    acc = fmaf(frelu(n7/d1 + bias2[7]), l2W[7], acc);
    x2a[n] = acc;
  }
}

// ---------------------------------------------------------------------------
__global__ void enc_finish(const float* __restrict__ encp, const float* __restrict__ x1,
                           const float* __restrict__ x2a,
                           const float* __restrict__ W1, const float* __restrict__ b1,
                           const float* __restrict__ W2, const float* __restrict__ b2,
                           const float* __restrict__ W3, const float* __restrict__ b3,
                           float* __restrict__ out){
  __shared__ float hb[4][64];
  int wv = threadIdx.x >> 6, lane = threadIdx.x & 63;
  int n = blockIdx.x*4 + wv;
  float hv = encp[n*64 + lane] + x1[n]*W1[9998*64 + lane]
           + x2a[n]*W1[9999*64 + lane] + b1[lane];
  hb[wv][lane] = frelu(hv);
  __syncthreads();
  float t = 0.f;
  if (lane < 32) {
    float a2 = b2[lane];
    #pragma unroll
    for (int k = 0; k < 64; ++k) a2 = fmaf(hb[wv][k], W2[k*32 + lane], a2);
    t = frelu(a2) * W3[lane];
  }
  #pragma unroll
  for (int m = 1; m < 64; m <<= 1) t += __shfl_xor(t, m, 64);
  if (lane == 0) out[n] = t + b3[0];
}

// ---------------------------------------------------------------------------
extern "C" void kernel_launch(void* const* d_in, const int* in_sizes, int n_in,
                              void* d_out, int out_size, void* d_ws, size_t ws_size,
                              hipStream_t stream){
  (void)in_sizes; (void)n_in; (void)out_size; (void)ws_size;
  const float* x    = (const float*)d_in[0];
  const int*   ei   = (const int*)  d_in[1];
  const float* Wl1  = (const float*)d_in[2];
  const float* bl1  = (const float*)d_in[3];
  const float* Wr1  = (const float*)d_in[4];
  const float* br1  = (const float*)d_in[5];
  const float* att1 = (const float*)d_in[6];
  const float* bias1= (const float*)d_in[7];
  const float* l1W  = (const float*)d_in[8];
  const float* l1b  = (const float*)d_in[9];
  const float* Wl2  = (const float*)d_in[10];
  const float* bl2  = (const float*)d_in[11];
  const float* Wr2  = (const float*)d_in[12];
  const float* br2  = (const float*)d_in[13];
  const float* att2 = (const float*)d_in[14];
  const float* bias2= (const float*)d_in[15];
  const float* l2W  = (const float*)d_in[16];
  const float* l2b  = (const float*)d_in[17];
  const float* eW1  = (const float*)d_in[18];
  const float* eb1  = (const float*)d_in[19];
  const float* eW2  = (const float*)d_in[20];
  const float* eb2  = (const float*)d_in[21];
  const float* eW3  = (const float*)d_in[22];
  const float* eb3  = (const float*)d_in[23];

  float* ws = (float*)d_ws;
  size_t off = 0;
  auto alloc = [&](size_t nel){ float* pp = ws + off; off += (nel + 63) & ~size_t(63); return pp; };
  _Float16* Wpad  = (_Float16*)alloc((size_t)KSL*WSLH/2);
  _Float16* slabh = (_Float16*)alloc((size_t)20*NSLAB/2);   // 32 MB
  float* xl1    = alloc(NNODE*8);
  float* xr1    = alloc(NNODE*8);
  float* encp   = alloc(NNODE*64);
  float* x1a    = alloc(NNODE);
  float* x2a    = alloc(NNODE);
  // int block [deg(10048), cnt(10048)] zeroed by prep_wt every launch:
  int*   deg    = (int*)alloc(NNODE);
  int*   cnt    = (int*)alloc(NNODE);
  int*   offs   = (int*)alloc(NNODE);
  int*   csrc   = (int*)alloc(NEDGE + NNODE);

  const int ET = NEDGE + NNODE;
  const int eb = (ET + 255)/256;

  prep_wt<<<(KSL*WSLH + 255)/256, 256, 0, stream>>>(Wl1, Wr1, eW1, Wpad, deg);

  k1_fused<<<157*20, 256, 0, stream>>>(x, Wpad, slabh);
  reduce80<<<(NSLAB + 255)/256, 256, 0, stream>>>(slabh, bl1, br1, xl1, xr1, encp);

  csr_hist<<<eb, 256, 0, stream>>>(ei, deg);
  csr_scan<<<1, 256, 0, stream>>>(deg, offs);
  csr_scat<<<eb, 256, 0, stream>>>(ei, offs, cnt, csrc);

  conv1_agg<<<(NNODE + 3)/4, 256, 0, stream>>>(offs, deg, csrc, xl1, xr1, att1,
                                               bias1, l1W, l1b, x1a);
  conv2_agg<<<(NNODE + 3)/4, 256, 0, stream>>>(offs, deg, csrc, x1a, Wl2, bl2,
                                               Wr2, br2, att2, bias2, l2W, l2b, x2a);

  enc_finish<<<NNODE/4, 256, 0, stream>>>(encp, x1a, x2a, eW1, eb1, eW2, eb2,
                                          eW3, eb3, (float*)d_out);
}

// Round 20
// 219.637 us; speedup vs baseline: 1.1616x; 1.1616x over previous
//
#include <hip/hip_runtime.h>
#include <math.h>

#define NNODE 10000
#define INCH  9998
#define NEDGE 320000
#define KSL   40           // K-slices of 256 (ks 0..39); k1 block does ks=j, j+20
#define WCOL  264          // padded k-stride of W slice (halves)
#define WSLH  21120        // halves per W slice: 80*264 (42240 B = 2640 uint4)
#define NSLAB 800000       // values per output slab (10000 x 80)
#define ZNI   20096        // ints zeroed: [deg(10048), cnt(10048)]

typedef _Float16 half8 __attribute__((ext_vector_type(8)));
typedef float    f32x4 __attribute__((ext_vector_type(4)));

__device__ __forceinline__ float lrelu(float v){ return v > 0.f ? v : 0.2f*v; }
__device__ __forceinline__ float frelu(float v){ return v > 0.f ? v : 0.f; }

#define RED1(v) { _Pragma("unroll") for (int m_ = 1; m_ < 64; m_ <<= 1) v += __shfl_xor(v, m_, 64); }

// ---------------------------------------------------------------------------
// Weight prep: Wpad[ks][col][kk] fp16, 256-K slices; zero-inits CSR counters.
// (r16 config — the measured optimum: r17 request-width null, r19 5-block TLP
// regressed 17%.)
__global__ void prep_wt(const float* __restrict__ Wl, const float* __restrict__ Wr,
                        const float* __restrict__ We, _Float16* __restrict__ Wpad,
                        int* __restrict__ zint){
  int idx = blockIdx.x*256 + threadIdx.x;
  if (idx < ZNI) zint[idx] = 0;
  if (idx >= KSL*WSLH) return;
  int ks  = idx / WSLH;
  int rem = idx - ks*WSLH;
  int col = rem / WCOL;
  int kk  = rem - col*WCOL;
  int k   = ks*256 + kk;
  float v = 0.f;
  if (kk < 256 && k < INCH)
    v = (col < 8) ? Wl[k*8 + col] : (col < 16 ? Wr[k*8 + (col-8)] : We[k*64 + (col-16)]);
  Wpad[idx] = (_Float16)v;
}

// ---------------------------------------------------------------------------
// k1: W LDS-resident fp16 GEMM (r15 structure, r16 tuning — PROVEN 219.7us).
#define XL(C, X0, X1, X2, X3) { \
  int kb_ = k0b + (C)*32 + 8*g; \
  X0 = *(const float2*)(x + min(xbase + kb_    , maxi)); \
  X1 = *(const float2*)(x + min(xbase + kb_ + 2, maxi)); \
  X2 = *(const float2*)(x + min(xbase + kb_ + 4, maxi)); \
  X3 = *(const float2*)(x + min(xbase + kb_ + 6, maxi)); }

#define CMP(C, X0, X1, X2, X3) { \
  half8 ah = {(_Float16)X0.x, (_Float16)X0.y, (_Float16)X1.x, (_Float16)X1.y, \
              (_Float16)X2.x, (_Float16)X2.y, (_Float16)X3.x, (_Float16)X3.y}; \
  const _Float16* wp_ = lw + (C)*32 + 8*g; \
  half8 b0 = *(const half8*)(wp_ + (c0     )*WCOL); \
  half8 b1 = *(const half8*)(wp_ + (c0 + 16)*WCOL); \
  half8 b2 = *(const half8*)(wp_ + (c0 + 32)*WCOL); \
  half8 b3 = *(const half8*)(wp_ + (c0 + 48)*WCOL); \
  half8 b4 = *(const half8*)(wp_ + (c0 + 64)*WCOL); \
  a0 = __builtin_amdgcn_mfma_f32_16x16x32_f16(ah, b0, a0, 0, 0, 0); \
  a1 = __builtin_amdgcn_mfma_f32_16x16x32_f16(ah, b1, a1, 0, 0, 0); \
  a2 = __builtin_amdgcn_mfma_f32_16x16x32_f16(ah, b2, a2, 0, 0, 0); \
  a3 = __builtin_amdgcn_mfma_f32_16x16x32_f16(ah, b3, a3, 0, 0, 0); \
  a4 = __builtin_amdgcn_mfma_f32_16x16x32_f16(ah, b4, a4, 0, 0, 0); }

__global__ __launch_bounds__(256, 3)
void k1_fused(const float* __restrict__ x, const _Float16* __restrict__ Wpad,
              _Float16* __restrict__ slabh){
  __shared__ _Float16 lw[WSLH];         // 42240 B -> 3 blocks/CU
  const int tid  = threadIdx.x;
  const int lane = tid & 63;
  const int wv   = tid >> 6;
  const int g    = lane >> 4;
  const int c0   = lane & 15;
  const int bid  = blockIdx.x;
  const int j    = bid / 157;           // output slab 0..19
  const int rb   = bid - j*157;         // row block 0..156
  const int arow = rb*64 + wv*16 + c0;
  const int xbase= (arow < NNODE ? arow : NNODE-1)*INCH;
  const int maxi = NNODE*INCH - 2;

  f32x4 a0={0,0,0,0}, a1={0,0,0,0}, a2={0,0,0,0}, a3={0,0,0,0}, a4={0,0,0,0};

  for (int h = 0; h < 2; ++h){          // 2 x 256-K phases: ks = j, j+20
    const int ks  = j + 20*h;
    const int k0b = ks << 8;
    if (h) __syncthreads();             // all waves done reading prev W slice
    {                                   // load W slice (2640 x 16B, coalesced)
      const uint4* src = (const uint4*)(Wpad + (size_t)ks*WSLH);
      uint4* dst = (uint4*)lw;
      #pragma unroll
      for (int i = 0; i < 11; ++i){
        int idx = tid + 256*i;
        if (idx < 2640) dst[idx] = src[idx];
      }
    }
    __syncthreads();                    // W visible; chunk loop barrier-free

    float2 xa0,xa1,xa2,xa3, xb0,xb1,xb2,xb3;
    XL(0, xa0,xa1,xa2,xa3)
    #pragma unroll
    for (int c = 0; c < 8; c += 2){     // 2-slot static pipeline (no reg moves)
      XL(c+1, xb0,xb1,xb2,xb3)
      CMP(c,   xa0,xa1,xa2,xa3)
      if (c + 2 < 8) XL(c+2, xa0,xa1,xa2,xa3)
      CMP(c+1, xb0,xb1,xb2,xb3)
    }
  }

  // epilogue: C/D layout col=lane&15, row=4*(lane>>4)+reg [m89-verified]
  const int nodeb = rb*64 + wv*16 + 4*g;
  #define EPI(T, A) { \
    _Pragma("unroll") \
    for (int r = 0; r < 4; ++r){ \
      int row = nodeb + r; \
      if (row < NNODE) \
        slabh[(size_t)j*NSLAB + (size_t)row*80 + 16*(T) + c0] = (_Float16)A[r]; \
    } }
  EPI(0, a0) EPI(1, a1) EPI(2, a2) EPI(3, a3) EPI(4, a4)
}

// ---------------------------------------------------------------------------
__global__ void reduce80(const _Float16* __restrict__ slabh, const float* __restrict__ bl1,
                         const float* __restrict__ br1, float* __restrict__ xl1,
                         float* __restrict__ xr1, float* __restrict__ encp){
  int f = blockIdx.x*256 + threadIdx.x;
  if (f >= NSLAB) return;
  float s = 0.f;
  #pragma unroll
  for (int k = 0; k < 20; ++k) s += (float)slabh[(size_t)k*NSLAB + f];
  int n = f / 80;
  int col = f - n*80;
  if (col < 8)       xl1[n*8 + col]        = s + bl1[col];
  else if (col < 16) xr1[n*8 + col - 8]    = s + br1[col - 8];
  else               encp[n*64 + col - 16] = s;
}

// ---------------------------------------------------------------------------
// CSR build (dst-grouped edge list incl. self-loops). deg/cnt pre-zeroed.
__global__ void csr_hist(const int* __restrict__ ei, int* __restrict__ deg){
  int e = blockIdx.x*256 + threadIdx.x;
  if (e >= NEDGE + NNODE) return;
  int d = (e < NEDGE) ? ei[NEDGE + e] : e - NEDGE;
  atomicAdd(deg + d, 1);
}

__global__ void csr_scan(const int* __restrict__ deg, int* __restrict__ offs){
  __shared__ int ssum[256];
  int t = threadIdx.x;
  int base = t*40;
  int s = 0;
  for (int i = 0; i < 40; ++i){
    int idx = base + i;
    s += (idx < NNODE) ? deg[idx] : 0;
  }
  ssum[t] = s;
  __syncthreads();
  for (int d = 1; d < 256; d <<= 1){
    int v = (t >= d) ? ssum[t - d] : 0;
    __syncthreads();
    ssum[t] += v;
    __syncthreads();
  }
  int run = (t == 0) ? 0 : ssum[t - 1];
  for (int i = 0; i < 40; ++i){
    int idx = base + i;
    if (idx < NNODE){ offs[idx] = run; run += deg[idx]; }
  }
}

__global__ void csr_scat(const int* __restrict__ ei, const int* __restrict__ offs,
                         int* __restrict__ cnt, int* __restrict__ csrc){
  int e = blockIdx.x*256 + threadIdx.x;
  if (e >= NEDGE + NNODE) return;
  int s, d;
  if (e < NEDGE){ s = ei[e]; d = ei[NEDGE + e]; } else { s = d = e - NEDGE; }
  int p = offs[d] + atomicAdd(cnt + d, 1);
  csrc[p] = s;
}

// ---------------------------------------------------------------------------
// conv1 aggregation, wave-per-dst, ONE pass, NO atomics.
__global__ __launch_bounds__(256)
void conv1_agg(const int* __restrict__ offs, const int* __restrict__ deg,
               const int* __restrict__ csrc, const float* __restrict__ xl1,
               const float* __restrict__ xr1, const float* __restrict__ att,
               const float* __restrict__ bias1, const float* __restrict__ linW,
               const float* __restrict__ linb, float* __restrict__ x1){
  int wv = threadIdx.x >> 6, lane = threadIdx.x & 63;
  int n = blockIdx.x*4 + wv;
  if (n >= NNODE) return;
  const int st = offs[n], en = st + deg[n];
  const float4 r0 = *(const float4*)(xr1 + n*8);
  const float4 r1 = *(const float4*)(xr1 + n*8 + 4);
  float at0=att[0], at1=att[1], at2=att[2], at3=att[3];
  float at4=att[4], at5=att[5], at6=att[6], at7=att[7];

  float d0=0.f, d1=0.f;
  float n0=0.f,n1=0.f,n2=0.f,n3=0.f,n4=0.f,n5=0.f,n6=0.f,n7=0.f;
  for (int i = st + lane; i < en; i += 64){
    int s = csrc[i];
    const float4 q0 = *(const float4*)(xl1 + s*8);
    const float4 q1 = *(const float4*)(xl1 + s*8 + 4);
    float l0 = at0*lrelu(q0.x+r0.x) + at1*lrelu(q0.y+r0.y)
             + at2*lrelu(q0.z+r0.z) + at3*lrelu(q0.w+r0.w);
    float l1 = at4*lrelu(q1.x+r1.x) + at5*lrelu(q1.y+r1.y)
             + at6*lrelu(q1.z+r1.z) + at7*lrelu(q1.w+r1.w);
    float e0 = expf(l0), e1 = expf(l1);
    d0 += e0; d1 += e1;
    n0 += e0*q0.x; n1 += e0*q0.y; n2 += e0*q0.z; n3 += e0*q0.w;
    n4 += e1*q1.x; n5 += e1*q1.y; n6 += e1*q1.z; n7 += e1*q1.w;
  }
  RED1(d0) RED1(d1)
  RED1(n0) RED1(n1) RED1(n2) RED1(n3)
  RED1(n4) RED1(n5) RED1(n6) RED1(n7)
  if (lane == 0){
    float acc = linb[0];
    acc = fmaf(frelu(n0/d0 + bias1[0]), linW[0], acc);
    acc = fmaf(frelu(n1/d0 + bias1[1]), linW[1], acc);
    acc = fmaf(frelu(n2/d0 + bias1[2]), linW[2], acc);
    acc = fmaf(frelu(n3/d0 + bias1[3]), linW[3], acc);
    acc = fmaf(frelu(n4/d1 + bias1[4]), linW[4], acc);
    acc = fmaf(frelu(n5/d1 + bias1[5]), linW[5], acc);
    acc = fmaf(frelu(n6/d1 + bias1[6]), linW[6], acc);
    acc = fmaf(frelu(n7/d1 + bias1[7]), linW[7], acc);
    x1[n] = acc;
  }
}

// ---------------------------------------------------------------------------
// conv2 aggregation (rank-1 from scalar x1) + x2 in-register.
__global__ __launch_bounds__(256)
void conv2_agg(const int* __restrict__ offs, const int* __restrict__ deg,
               const int* __restrict__ csrc, const float* __restrict__ x1,
               const float* __restrict__ Wl2, const float* __restrict__ bl2,
               const float* __restrict__ Wr2, const float* __restrict__ br2,
               const float* __restrict__ att, const float* __restrict__ bias2,
               const float* __restrict__ l2W, const float* __restrict__ l2b,
               float* __restrict__ x2a){
  int wv = threadIdx.x >> 6, lane = threadIdx.x & 63;
  int n = blockIdx.x*4 + wv;
  if (n >= NNODE) return;
  const int st = offs[n], en = st + deg[n];
  const float xd = x1[n];
  float wr[8], wl[8], blv[8], atv[8];
  #pragma unroll
  for (int c = 0; c < 8; ++c){
    wr[c]  = fmaf(xd, Wr2[c], br2[c]);
    wl[c]  = Wl2[c];
    blv[c] = bl2[c];
    atv[c] = att[c];
  }
  float d0=0.f, d1=0.f;
  float n0=0.f,n1=0.f,n2=0.f,n3=0.f,n4=0.f,n5=0.f,n6=0.f,n7=0.f;
  for (int i = st + lane; i < en; i += 64){
    float xs = x1[csrc[i]];
    float f0 = fmaf(xs, wl[0], blv[0]);
    float f1 = fmaf(xs, wl[1], blv[1]);
    float f2 = fmaf(xs, wl[2], blv[2]);
    float f3 = fmaf(xs, wl[3], blv[3]);
    float f4 = fmaf(xs, wl[4], blv[4]);
    float f5 = fmaf(xs, wl[5], blv[5]);
    float f6 = fmaf(xs, wl[6], blv[6]);
    float f7 = fmaf(xs, wl[7], blv[7]);
    float l0 = atv[0]*lrelu(f0+wr[0]) + atv[1]*lrelu(f1+wr[1])
             + atv[2]*lrelu(f2+wr[2]) + atv[3]*lrelu(f3+wr[3]);
    float l1 = atv[4]*lrelu(f4+wr[4]) + atv[5]*lrelu(f5+wr[5])
             + atv[6]*lrelu(f6+wr[6]) + atv[7]*lrelu(f7+wr[7]);
    float e0 = expf(l0), e1 = expf(l1);
    d0 += e0; d1 += e1;
    n0 += e0*f0; n1 += e0*f1; n2 += e0*f2; n3 += e0*f3;
    n4 += e1*f4; n5 += e1*f5; n6 += e1*f6; n7 += e1*f7;
  }
  RED1(d0) RED1(d1)
  RED1(n0) RED1(n1) RED1(n2) RED1(n3)
  RED1(n4) RED1(n5) RED1(n6) RED1(n7)
  if (lane == 0){
    float acc = l2b[0];
    acc = fmaf(frelu(n0/d0 + bias2[0]), l2W[0], acc);
    acc = fmaf(frelu(n1/d0 + bias2[1]), l2W[1], acc);
    acc = fmaf(frelu(n2/d0 + bias2[2]), l2W[2], acc);
    acc = fmaf(frelu(n3/d0 + bias2[3]), l2W[3], acc);
    acc = fmaf(frelu(n4/d1 + bias2[4]), l2W[4], acc);
    acc = fmaf(frelu(n5/d1 + bias2[5]), l2W[5], acc);
    acc = fmaf(frelu(n6/d1 + bias2[6]), l2W[6], acc);
    acc = fmaf(frelu(n7/d1 + bias2[7]), l2W[7], acc);
    x2a[n] = acc;
  }
}

// ---------------------------------------------------------------------------
__global__ void enc_finish(const float* __restrict__ encp, const float* __restrict__ x1,
                           const float* __restrict__ x2a,
                           const float* __restrict__ W1, const float* __restrict__ b1,
                           const float* __restrict__ W2, const float* __restrict__ b2,
                           const float* __restrict__ W3, const float* __restrict__ b3,
                           float* __restrict__ out){
  __shared__ float hb[4][64];
  int wv = threadIdx.x >> 6, lane = threadIdx.x & 63;
  int n = blockIdx.x*4 + wv;
  float hv = encp[n*64 + lane] + x1[n]*W1[9998*64 + lane]
           + x2a[n]*W1[9999*64 + lane] + b1[lane];
  hb[wv][lane] = frelu(hv);
  __syncthreads();
  float t = 0.f;
  if (lane < 32) {
    float a2 = b2[lane];
    #pragma unroll
    for (int k = 0; k < 64; ++k) a2 = fmaf(hb[wv][k], W2[k*32 + lane], a2);
    t = frelu(a2) * W3[lane];
  }
  #pragma unroll
  for (int m = 1; m < 64; m <<= 1) t += __shfl_xor(t, m, 64);
  if (lane == 0) out[n] = t + b3[0];
}

// ---------------------------------------------------------------------------
extern "C" void kernel_launch(void* const* d_in, const int* in_sizes, int n_in,
                              void* d_out, int out_size, void* d_ws, size_t ws_size,
                              hipStream_t stream){
  (void)in_sizes; (void)n_in; (void)out_size; (void)ws_size;
  const float* x    = (const float*)d_in[0];
  const int*   ei   = (const int*)  d_in[1];
  const float* Wl1  = (const float*)d_in[2];
  const float* bl1  = (const float*)d_in[3];
  const float* Wr1  = (const float*)d_in[4];
  const float* br1  = (const float*)d_in[5];
  const float* att1 = (const float*)d_in[6];
  const float* bias1= (const float*)d_in[7];
  const float* l1W  = (const float*)d_in[8];
  const float* l1b  = (const float*)d_in[9];
  const float* Wl2  = (const float*)d_in[10];
  const float* bl2  = (const float*)d_in[11];
  const float* Wr2  = (const float*)d_in[12];
  const float* br2  = (const float*)d_in[13];
  const float* att2 = (const float*)d_in[14];
  const float* bias2= (const float*)d_in[15];
  const float* l2W  = (const float*)d_in[16];
  const float* l2b  = (const float*)d_in[17];
  const float* eW1  = (const float*)d_in[18];
  const float* eb1  = (const float*)d_in[19];
  const float* eW2  = (const float*)d_in[20];
  const float* eb2  = (const float*)d_in[21];
  const float* eW3  = (const float*)d_in[22];
  const float* eb3  = (const float*)d_in[23];

  float* ws = (float*)d_ws;
  size_t off = 0;
  auto alloc = [&](size_t nel){ float* pp = ws + off; off += (nel + 63) & ~size_t(63); return pp; };
  _Float16* Wpad  = (_Float16*)alloc((size_t)KSL*WSLH/2);
  _Float16* slabh = (_Float16*)alloc((size_t)20*NSLAB/2);   // 32 MB
  float* xl1    = alloc(NNODE*8);
  float* xr1    = alloc(NNODE*8);
  float* encp   = alloc(NNODE*64);
  float* x1a    = alloc(NNODE);
  float* x2a    = alloc(NNODE);
  // int block [deg(10048), cnt(10048)] zeroed by prep_wt every launch:
  int*   deg    = (int*)alloc(NNODE);
  int*   cnt    = (int*)alloc(NNODE);
  int*   offs   = (int*)alloc(NNODE);
  int*   csrc   = (int*)alloc(NEDGE + NNODE);

  const int ET = NEDGE + NNODE;
  const int eb = (ET + 255)/256;

  prep_wt<<<(KSL*WSLH + 255)/256, 256, 0, stream>>>(Wl1, Wr1, eW1, Wpad, deg);

  k1_fused<<<157*20, 256, 0, stream>>>(x, Wpad, slabh);
  reduce80<<<(NSLAB + 255)/256, 256, 0, stream>>>(slabh, bl1, br1, xl1, xr1, encp);

  csr_hist<<<eb, 256, 0, stream>>>(ei, deg);
  csr_scan<<<1, 256, 0, stream>>>(deg, offs);
  csr_scat<<<eb, 256, 0, stream>>>(ei, offs, cnt, csrc);

  conv1_agg<<<(NNODE + 3)/4, 256, 0, stream>>>(offs, deg, csrc, xl1, xr1, att1,
                                               bias1, l1W, l1b, x1a);
  conv2_agg<<<(NNODE + 3)/4, 256, 0, stream>>>(offs, deg, csrc, x1a, Wl2, bl2,
                                               Wr2, br2, att2, bias2, l2W, l2b, x2a);

  enc_finish<<<NNODE/4, 256, 0, stream>>>(encp, x1a, x2a, eW1, eb1, eW2, eb2,
                                          eW3, eb3, (float*)d_out);
}